// Round 4
// baseline (106.622 us; speedup 1.0000x reference)
//
#include <hip/hip_runtime.h>
#include <math.h>

#define NPIX   4096
#define FDIM   64
#define BATCH  2
#define SPLIT  16
#define CHUNK  (NPIX / SPLIT)      // 256
#define NGROUP (CHUNK / 64)        // 4 groups of 64 cols

typedef __attribute__((ext_vector_type(8))) short short8;
typedef __attribute__((ext_vector_type(4))) float floatx4;

__device__ __forceinline__ float exp2f_(float x) { return __builtin_amdgcn_exp2f(x); }

// round-to-nearest-even fp32 -> bf16
__device__ __forceinline__ short f2bf(float x) {
    union { float f; unsigned u; } c; c.f = x;
    unsigned r = (c.u + 0x7FFFu + ((c.u >> 16) & 1u)) >> 16;
    return (short)r;
}

// ---------------- LAB helpers ----------------
__device__ __forceinline__ float gamma_expand(float u) {
    return u > 0.04045f ? powf((u + 0.055f) * (1.0f / 1.055f), 2.4f)
                        : u * (1.0f / 12.92f);
}
__device__ __forceinline__ float lab_f(float t) {
    return t > 0.008856f ? cbrtf(t) : 7.787f * t + (16.0f / 116.0f);
}

// ---------------- Kernel 1: prep = feat transpose->bf16 (blocks 0..255) + LAB (blocks 256..319) ----
// f0t/f1t: [b][n][f] bf16; f0t pre-scaled by log2(e)/0.07 (logits in log2 space).
__global__ __launch_bounds__(256) void prep_kernel(
    const float* __restrict__ rgb0, const float* __restrict__ rgb1,
    const float* __restrict__ feat0, const float* __restrict__ feat1,
    float* __restrict__ lab0, float* __restrict__ lab1,
    short* __restrict__ f0t, short* __restrict__ f1t,
    float* __restrict__ out)
{
    int bid = blockIdx.x;
    int tid = threadIdx.x;

    if (bid < 256) {
        __shared__ short Tsm[64 * 72];
        int pair = bid >> 6;            // 0..3
        int tensor = pair >> 1;         // 0: f0, 1: f1
        int bb = pair & 1;
        int n0 = (bid & 63) * 64;
        const float* src = (tensor ? feat1 : feat0) + (size_t)bb * FDIM * NPIX;
        short* dst = (tensor ? f1t : f0t) + (size_t)bb * NPIX * FDIM;
        float scale = tensor ? 1.0f : (1.442695040888963f / 0.07f);

        int f = tid >> 2;
        int slot = tid & 3;
        #pragma unroll
        for (int i = 0; i < 4; ++i) {
            int col4 = slot * 4 + i;
            int noff = col4 * 4;
            float4 v = *(const float4*)&src[(size_t)f * NPIX + n0 + noff];
            Tsm[(noff + 0) * 72 + f] = f2bf(v.x * scale);
            Tsm[(noff + 1) * 72 + f] = f2bf(v.y * scale);
            Tsm[(noff + 2) * 72 + f] = f2bf(v.z * scale);
            Tsm[(noff + 3) * 72 + f] = f2bf(v.w * scale);
        }
        __syncthreads();
        #pragma unroll
        for (int i = 0; i < 2; ++i) {
            int idx = i * 256 + tid;
            int row = idx >> 3, ch = idx & 7;
            *(short8*)&dst[(size_t)(n0 + row) * FDIM + ch * 8] =
                *(const short8*)&Tsm[row * 72 + ch * 8];
        }
        return;
    }

    if (bid == 256 && tid == 0) out[0] = 0.0f;   // zero-init for loss atomicAdd

    // LAB branch
    int gid = (bid - 256) * 256 + tid;     // 0 .. 16383
    int img = gid / (BATCH * NPIX);
    int rem = gid - img * (BATCH * NPIX);
    int b = rem / NPIX;
    int n = rem - b * NPIX;
    const float* rgb = img ? rgb1 : rgb0;
    float* lab = img ? lab1 : lab0;

    size_t i0 = (size_t)(b * 3 + 0) * NPIX + n;
    size_t i1 = (size_t)(b * 3 + 1) * NPIX + n;
    size_t i2 = (size_t)(b * 3 + 2) * NPIX + n;

    float r = gamma_expand(rgb[i0] + 0.5f);
    float g = gamma_expand(rgb[i1] + 0.5f);
    float bl = gamma_expand(rgb[i2] + 0.5f);

    float X = (0.412453f * r + 0.357580f * g + 0.180423f * bl) * (1.0f / 0.95047f);
    float Y = (0.212671f * r + 0.715160f * g + 0.072169f * bl);
    float Z = (0.019334f * r + 0.119193f * g + 0.950227f * bl) * (1.0f / 1.08883f);

    float fx = lab_f(X), fy = lab_f(Y), fz = lab_f(Z);
    float L = 116.0f * fy - 16.0f;
    float a = 500.0f * (fx - fy);
    float bb2 = 200.0f * (fy - fz);

    lab[i0] = (L - 50.0f) * (1.0f / 100.0f);
    lab[i1] = a * (1.0f / 110.0f);
    lab[i2] = bb2 * (1.0f / 110.0f);
}

// ---------------- Kernel 2: MFMA attn, barrier-free main loop ----------------
// B fragments load straight from global f1t (same lane layout as A: [m=lane&15][k=q*8+j]).
// Labels for the block's whole m-chunk staged once in LDS (one barrier total).
__global__ __launch_bounds__(256, 4) void attn_kernel(
    const short* __restrict__ f0t, const short* __restrict__ f1t,
    const float* __restrict__ lab1ws, float* __restrict__ partials)
{
    __shared__ float Lt[3 * CHUNK];    // 768 floats

    int bid = blockIdx.x;
    int rowblk = bid & 63;             // 64 rowblocks of 64 rows
    int chunk = (bid >> 6) & (SPLIT - 1);
    int b = bid >> 10;
    int n0 = rowblk * 64;
    int m_base = chunk * CHUNK;

    int tid = threadIdx.x;
    int w = tid >> 6;
    int l = tid & 63;
    int c = l & 15;
    int q = l >> 4;

    // stage labels for the whole m-chunk (3 x 256 floats), conflict-free reads later
    if (tid < 192) {
        int cc = tid >> 6;             // 64 float4 per channel
        int m4 = tid & 63;
        *(float4*)&Lt[cc * CHUNK + m4 * 4] =
            *(const float4*)&lab1ws[(size_t)(b * 3 + cc) * NPIX + m_base + m4 * 4];
    }

    // A fragments (row block n0 + w*16): A[m=c][k=q*8+j], k-halves
    const short8* aptr = (const short8*)(f0t +
        ((size_t)b * NPIX + n0 + w * 16 + c) * FDIM + q * 8);
    short8 a0 = aptr[0];
    short8 a1 = aptr[4];               // +32 shorts

    __syncthreads();

    float m_st[4], sum_st[4], s0_st[4], s1_st[4], s2_st[4];
    #pragma unroll
    for (int r = 0; r < 4; ++r) {
        m_st[r] = -INFINITY; sum_st[r] = 0.0f;
        s0_st[r] = 0.0f; s1_st[r] = 0.0f; s2_st[r] = 0.0f;
    }

    const short8* bbase = (const short8*)(f1t +
        ((size_t)b * NPIX + m_base + c) * FDIM + q * 8);

    #pragma unroll
    for (int g = 0; g < NGROUP; ++g) {
        // B fragments for 4 tiles of 16 cols, straight from global (L1/L2 resident)
        floatx4 acc[4];
        #pragma unroll
        for (int t = 0; t < 4; ++t) {
            const short8* bp = bbase + (size_t)(g * 64 + t * 16) * 8;  // rows are 8 short8
            short8 b0 = bp[0];
            short8 b1 = bp[4];
            floatx4 z = (floatx4)(0.0f);
            acc[t] = __builtin_amdgcn_mfma_f32_16x16x32_bf16(a0, b0, z, 0, 0, 0);
            acc[t] = __builtin_amdgcn_mfma_f32_16x16x32_bf16(a1, b1, acc[t], 0, 0, 0);
        }

        float lA[4], lB[4], lC[4];
        #pragma unroll
        for (int t = 0; t < 4; ++t) {
            int m = g * 64 + t * 16 + c;
            lA[t] = Lt[0 * CHUNK + m];
            lB[t] = Lt[1 * CHUNK + m];
            lC[t] = Lt[2 * CHUNK + m];
        }

        #pragma unroll
        for (int r = 0; r < 4; ++r) {
            float L0 = acc[0][r], L1 = acc[1][r], L2 = acc[2][r], L3 = acc[3][r];
            float tmax = fmaxf(fmaxf(L0, L1), fmaxf(L2, L3));
            float nm = fmaxf(m_st[r], tmax);
            float sc = exp2f_(m_st[r] - nm);
            float p0 = exp2f_(L0 - nm);
            float p1 = exp2f_(L1 - nm);
            float p2 = exp2f_(L2 - nm);
            float p3 = exp2f_(L3 - nm);
            sum_st[r] = sum_st[r] * sc + ((p0 + p1) + (p2 + p3));
            s0_st[r] = s0_st[r] * sc + ((p0 * lA[0] + p1 * lA[1]) + (p2 * lA[2] + p3 * lA[3]));
            s1_st[r] = s1_st[r] * sc + ((p0 * lB[0] + p1 * lB[1]) + (p2 * lB[2] + p3 * lB[3]));
            s2_st[r] = s2_st[r] * sc + ((p0 * lC[0] + p1 * lC[1]) + (p2 * lC[2] + p3 * lC[3]));
            m_st[r] = nm;
        }
    }

    // butterfly merge across the 16 col-class lanes of each quad
    #pragma unroll
    for (int mask = 1; mask <= 8; mask <<= 1) {
        #pragma unroll
        for (int r = 0; r < 4; ++r) {
            float om = __shfl_xor(m_st[r], mask, 64);
            float os = __shfl_xor(sum_st[r], mask, 64);
            float o0 = __shfl_xor(s0_st[r], mask, 64);
            float o1 = __shfl_xor(s1_st[r], mask, 64);
            float o2 = __shfl_xor(s2_st[r], mask, 64);
            float nm = fmaxf(m_st[r], om);
            float w1 = exp2f_(m_st[r] - nm);
            float w2 = exp2f_(om - nm);
            sum_st[r] = sum_st[r] * w1 + os * w2;
            s0_st[r] = s0_st[r] * w1 + o0 * w2;
            s1_st[r] = s1_st[r] * w1 + o1 * w2;
            s2_st[r] = s2_st[r] * w1 + o2 * w2;
            m_st[r] = nm;
        }
    }

    if (c == 0) {
        #pragma unroll
        for (int r = 0; r < 4; ++r) {
            int row_g = n0 + w * 16 + q * 4 + r;
            size_t base = (size_t)(b * SPLIT + chunk) * 5 * NPIX + row_g;
            partials[base + 0 * NPIX] = m_st[r];
            partials[base + 1 * NPIX] = sum_st[r];
            partials[base + 2 * NPIX] = s0_st[r];
            partials[base + 3 * NPIX] = s1_st[r];
            partials[base + 4 * NPIX] = s2_st[r];
        }
    }
}

// ---------------- Kernel 3: merge chunks, diff, L1+Huber, reduce ----------------
__global__ void loss_kernel(const float* __restrict__ partials,
                            const float* __restrict__ lab0ws,
                            float* __restrict__ out)
{
    int gid = blockIdx.x * blockDim.x + threadIdx.x;   // 0..8191
    int b = gid >> 12;
    int n = gid & (NPIX - 1);

    float M = -INFINITY;
    #pragma unroll
    for (int ch = 0; ch < SPLIT; ++ch)
        M = fmaxf(M, partials[((size_t)(b * SPLIT + ch) * 5 + 0) * NPIX + n]);
    float S = 0.0f, A0 = 0.0f, A1 = 0.0f, A2 = 0.0f;
    #pragma unroll
    for (int ch = 0; ch < SPLIT; ++ch) {
        size_t base = (size_t)(b * SPLIT + ch) * 5 * NPIX + n;
        float w = exp2f_(partials[base + 0 * NPIX] - M);
        S  += partials[base + 1 * NPIX] * w;
        A0 += partials[base + 2 * NPIX] * w;
        A1 += partials[base + 3 * NPIX] * w;
        A2 += partials[base + 4 * NPIX] * w;
    }
    float inv_s = 1.0f / S;
    float d0 = A0 * inv_s - lab0ws[(size_t)(b * 3 + 0) * NPIX + n];
    float d1 = A1 * inv_s - lab0ws[(size_t)(b * 3 + 1) * NPIX + n];
    float d2 = A2 * inv_s - lab0ws[(size_t)(b * 3 + 2) * NPIX + n];

    float val = 0.0f;
    #pragma unroll
    for (int cc = 0; cc < 3; ++cc) {
        float d = (cc == 0) ? d0 : (cc == 1) ? d1 : d2;
        float ad = fabsf(d);
        float hub = (ad < 1.0f) ? 0.5f * ad * ad : ad - 0.5f;
        val += ad + hub;
    }

    #pragma unroll
    for (int off = 32; off > 0; off >>= 1)
        val += __shfl_down(val, off);

    __shared__ float wsum[4];
    int lane = threadIdx.x & 63;
    int wave = threadIdx.x >> 6;
    if (lane == 0) wsum[wave] = val;
    __syncthreads();
    if (threadIdx.x == 0) {
        float s = wsum[0] + wsum[1] + wsum[2] + wsum[3];
        atomicAdd(out, s * (1.0f / 8192.0f));
    }
}

// ---------------- launcher ----------------
extern "C" void kernel_launch(void* const* d_in, const int* in_sizes, int n_in,
                              void* d_out, int out_size, void* d_ws, size_t ws_size,
                              hipStream_t stream) {
    const float* rgb0  = (const float*)d_in[0];
    const float* rgb1  = (const float*)d_in[1];
    const float* feat0 = (const float*)d_in[2];
    const float* feat1 = (const float*)d_in[3];
    float* out = (float*)d_out;
    float* ws  = (float*)d_ws;

    float* lab0 = ws;                         // 24576 floats
    float* lab1 = ws + 24576;                 // 24576 floats
    float* partials = ws + 49152;             // 2*16*5*4096 = 655360 floats
    short* f0t = (short*)(ws + 49152 + 655360);
    short* f1t = f0t + (size_t)BATCH * NPIX * FDIM;

    prep_kernel<<<320, 256, 0, stream>>>(rgb0, rgb1, feat0, feat1, lab0, lab1, f0t, f1t, out);

    int attn_grid = BATCH * SPLIT * (NPIX / 64);   // 2048
    attn_kernel<<<attn_grid, 256, 0, stream>>>(f0t, f1t, lab1, partials);

    loss_kernel<<<(BATCH * NPIX) / 256, 256, 0, stream>>>(partials, lab0, out);
}

// Round 5
// 93.667 us; speedup vs baseline: 1.1383x; 1.1383x over previous
//
#include <hip/hip_runtime.h>
#include <math.h>

#define NPIX   4096
#define FDIM   64
#define BATCH  2
#define SPLIT  16
#define CHUNK  (NPIX / SPLIT)      // 256
#define NTILE  (CHUNK / 16)        // 16 m-tiles of 16

typedef __attribute__((ext_vector_type(8))) short short8;
typedef __attribute__((ext_vector_type(4))) float floatx4;

__device__ __forceinline__ float exp2f_(float x) { return __builtin_amdgcn_exp2f(x); }

// round-to-nearest-even fp32 -> bf16
__device__ __forceinline__ short f2bf(float x) {
    union { float f; unsigned u; } c; c.f = x;
    unsigned r = (c.u + 0x7FFFu + ((c.u >> 16) & 1u)) >> 16;
    return (short)r;
}

// ---------------- LAB helpers ----------------
__device__ __forceinline__ float gamma_expand(float u) {
    return u > 0.04045f ? powf((u + 0.055f) * (1.0f / 1.055f), 2.4f)
                        : u * (1.0f / 12.92f);
}
__device__ __forceinline__ float lab_f(float t) {
    return t > 0.008856f ? cbrtf(t) : 7.787f * t + (16.0f / 116.0f);
}

// ---------------- Kernel 1: prep = feat transpose->bf16 (blocks 0..255) + LAB (blocks 256..319) ----
// f0t/f1t: [b][n][f] bf16; f0t pre-scaled by log2(e)/0.07 (logits in log2 space).
__global__ __launch_bounds__(256) void prep_kernel(
    const float* __restrict__ rgb0, const float* __restrict__ rgb1,
    const float* __restrict__ feat0, const float* __restrict__ feat1,
    float* __restrict__ lab0, float* __restrict__ lab1,
    short* __restrict__ f0t, short* __restrict__ f1t,
    float* __restrict__ out)
{
    int bid = blockIdx.x;
    int tid = threadIdx.x;

    if (bid < 256) {
        __shared__ short Tsm[64 * 72];
        int pair = bid >> 6;            // 0..3
        int tensor = pair >> 1;         // 0: f0, 1: f1
        int bb = pair & 1;
        int n0 = (bid & 63) * 64;
        const float* src = (tensor ? feat1 : feat0) + (size_t)bb * FDIM * NPIX;
        short* dst = (tensor ? f1t : f0t) + (size_t)bb * NPIX * FDIM;
        float scale = tensor ? 1.0f : (1.442695040888963f / 0.07f);

        int f = tid >> 2;
        int slot = tid & 3;
        #pragma unroll
        for (int i = 0; i < 4; ++i) {
            int col4 = slot * 4 + i;
            int noff = col4 * 4;
            float4 v = *(const float4*)&src[(size_t)f * NPIX + n0 + noff];
            Tsm[(noff + 0) * 72 + f] = f2bf(v.x * scale);
            Tsm[(noff + 1) * 72 + f] = f2bf(v.y * scale);
            Tsm[(noff + 2) * 72 + f] = f2bf(v.z * scale);
            Tsm[(noff + 3) * 72 + f] = f2bf(v.w * scale);
        }
        __syncthreads();
        #pragma unroll
        for (int i = 0; i < 2; ++i) {
            int idx = i * 256 + tid;
            int row = idx >> 3, ch = idx & 7;
            *(short8*)&dst[(size_t)(n0 + row) * FDIM + ch * 8] =
                *(const short8*)&Tsm[row * 72 + ch * 8];
        }
        return;
    }

    if (bid == 256 && tid == 0) out[0] = 0.0f;   // zero-init for loss atomicAdd

    // LAB branch
    int gid = (bid - 256) * 256 + tid;     // 0 .. 16383
    int img = gid / (BATCH * NPIX);
    int rem = gid - img * (BATCH * NPIX);
    int b = rem / NPIX;
    int n = rem - b * NPIX;
    const float* rgb = img ? rgb1 : rgb0;
    float* lab = img ? lab1 : lab0;

    size_t i0 = (size_t)(b * 3 + 0) * NPIX + n;
    size_t i1 = (size_t)(b * 3 + 1) * NPIX + n;
    size_t i2 = (size_t)(b * 3 + 2) * NPIX + n;

    float r = gamma_expand(rgb[i0] + 0.5f);
    float g = gamma_expand(rgb[i1] + 0.5f);
    float bl = gamma_expand(rgb[i2] + 0.5f);

    float X = (0.412453f * r + 0.357580f * g + 0.180423f * bl) * (1.0f / 0.95047f);
    float Y = (0.212671f * r + 0.715160f * g + 0.072169f * bl);
    float Z = (0.019334f * r + 0.119193f * g + 0.950227f * bl) * (1.0f / 1.08883f);

    float fx = lab_f(X), fy = lab_f(Y), fz = lab_f(Z);
    float L = 116.0f * fy - 16.0f;
    float a = 500.0f * (fx - fy);
    float bb2 = 200.0f * (fy - fz);

    lab[i0] = (L - 50.0f) * (1.0f / 100.0f);
    lab[i1] = a * (1.0f / 110.0f);
    lab[i2] = bb2 * (1.0f / 110.0f);
}

// ---------------- Kernel 2: MFMA attn, operand-swapped, register-pipelined ----------------
// mfma(X=f1 rows m, Y=f0 rows n): D[row=q*4+r <-> m][col=lane&15 <-> n].
// Per-lane online-softmax state = ONE n-row (per n-group); merge = 2 butterfly steps over q.
// No LDS, no barriers; labels broadcast-loaded from global; X/labels double-buffered in regs.
__global__ __launch_bounds__(256, 4) void attn_kernel(
    const short* __restrict__ f0t, const short* __restrict__ f1t,
    const float* __restrict__ lab1ws, float* __restrict__ partials)
{
    int bid = blockIdx.x;
    int rowblk = bid & 31;                 // 32 rowblocks of 128 n-rows
    int chunk = (bid >> 5) & (SPLIT - 1);
    int b = bid >> 9;
    int tid = threadIdx.x;
    int w = tid >> 6;
    int l = tid & 63;
    int c = l & 15;
    int q = l >> 4;

    int n_base = rowblk * 128 + w * 32;    // this wave: n_base..+15 (g0), +16..+31 (g1)
    int m_base = chunk * CHUNK;

    // Y fragments (f0, n-rows), two groups
    const short8* yp0 = (const short8*)(f0t + ((size_t)b * NPIX + n_base + c) * FDIM + q * 8);
    short8 y0a = yp0[0], y0b = yp0[4];
    const short8* yp1 = (const short8*)(f0t + ((size_t)b * NPIX + n_base + 16 + c) * FDIM + q * 8);
    short8 y1a = yp1[0], y1b = yp1[4];

    // X base (f1, m-rows): lane c -> row m_base + c; tile t advances 16 rows = 128 short8
    const short8* xbase = (const short8*)(f1t + ((size_t)b * NPIX + m_base + c) * FDIM + q * 8);
    const float* labA = lab1ws + (size_t)(b * 3 + 0) * NPIX + m_base + q * 4;
    const float* labB = lab1ws + (size_t)(b * 3 + 1) * NPIX + m_base + q * 4;
    const float* labC = lab1ws + (size_t)(b * 3 + 2) * NPIX + m_base + q * 4;

    float m0s = -INFINITY, sum0 = 0.0f, a0A = 0.0f, a0B = 0.0f, a0C = 0.0f;
    float m1s = -INFINITY, sum1 = 0.0f, a1A = 0.0f, a1B = 0.0f, a1C = 0.0f;

    // prime the pipeline
    short8 xa = xbase[0], xb = xbase[4];
    float4 lA = *(const float4*)labA;
    float4 lB = *(const float4*)labB;
    float4 lC = *(const float4*)labC;

    #pragma unroll
    for (int t = 0; t < NTILE; ++t) {
        short8 xa_n, xb_n;
        float4 lA_n, lB_n, lC_n;
        if (t + 1 < NTILE) {
            const short8* xp = xbase + (size_t)(t + 1) * 128;
            xa_n = xp[0];
            xb_n = xp[4];
            lA_n = *(const float4*)(labA + (t + 1) * 16);
            lB_n = *(const float4*)(labB + (t + 1) * 16);
            lC_n = *(const float4*)(labC + (t + 1) * 16);
        }

        floatx4 z = (floatx4)(0.0f);
        floatx4 acc0 = __builtin_amdgcn_mfma_f32_16x16x32_bf16(xa, y0a, z, 0, 0, 0);
        acc0 = __builtin_amdgcn_mfma_f32_16x16x32_bf16(xb, y0b, acc0, 0, 0, 0);
        floatx4 acc1 = __builtin_amdgcn_mfma_f32_16x16x32_bf16(xa, y1a, z, 0, 0, 0);
        acc1 = __builtin_amdgcn_mfma_f32_16x16x32_bf16(xb, y1b, acc1, 0, 0, 0);

        // state 0 update (n-group 0): 4 m-logits of one row
        {
            float L0 = acc0[0], L1 = acc0[1], L2 = acc0[2], L3 = acc0[3];
            float tmax = fmaxf(fmaxf(L0, L1), fmaxf(L2, L3));
            float nm = fmaxf(m0s, tmax);
            float sc = exp2f_(m0s - nm);
            float p0 = exp2f_(L0 - nm);
            float p1 = exp2f_(L1 - nm);
            float p2 = exp2f_(L2 - nm);
            float p3 = exp2f_(L3 - nm);
            sum0 = sum0 * sc + ((p0 + p1) + (p2 + p3));
            a0A = a0A * sc + ((p0 * lA.x + p1 * lA.y) + (p2 * lA.z + p3 * lA.w));
            a0B = a0B * sc + ((p0 * lB.x + p1 * lB.y) + (p2 * lB.z + p3 * lB.w));
            a0C = a0C * sc + ((p0 * lC.x + p1 * lC.y) + (p2 * lC.z + p3 * lC.w));
            m0s = nm;
        }
        // state 1 update (n-group 1)
        {
            float L0 = acc1[0], L1 = acc1[1], L2 = acc1[2], L3 = acc1[3];
            float tmax = fmaxf(fmaxf(L0, L1), fmaxf(L2, L3));
            float nm = fmaxf(m1s, tmax);
            float sc = exp2f_(m1s - nm);
            float p0 = exp2f_(L0 - nm);
            float p1 = exp2f_(L1 - nm);
            float p2 = exp2f_(L2 - nm);
            float p3 = exp2f_(L3 - nm);
            sum1 = sum1 * sc + ((p0 + p1) + (p2 + p3));
            a1A = a1A * sc + ((p0 * lA.x + p1 * lA.y) + (p2 * lA.z + p3 * lA.w));
            a1B = a1B * sc + ((p0 * lB.x + p1 * lB.y) + (p2 * lB.z + p3 * lB.w));
            a1C = a1C * sc + ((p0 * lC.x + p1 * lC.y) + (p2 * lC.z + p3 * lC.w));
            m1s = nm;
        }

        if (t + 1 < NTILE) {
            xa = xa_n; xb = xb_n;
            lA = lA_n; lB = lB_n; lC = lC_n;
        }
    }

    // butterfly merge across q (lane bits 4-5): 2 steps
    #pragma unroll
    for (int mask = 16; mask <= 32; mask <<= 1) {
        {
            float om = __shfl_xor(m0s, mask, 64);
            float os = __shfl_xor(sum0, mask, 64);
            float oA = __shfl_xor(a0A, mask, 64);
            float oB = __shfl_xor(a0B, mask, 64);
            float oC = __shfl_xor(a0C, mask, 64);
            float nm = fmaxf(m0s, om);
            float w1 = exp2f_(m0s - nm);
            float w2 = exp2f_(om - nm);
            sum0 = sum0 * w1 + os * w2;
            a0A = a0A * w1 + oA * w2;
            a0B = a0B * w1 + oB * w2;
            a0C = a0C * w1 + oC * w2;
            m0s = nm;
        }
        {
            float om = __shfl_xor(m1s, mask, 64);
            float os = __shfl_xor(sum1, mask, 64);
            float oA = __shfl_xor(a1A, mask, 64);
            float oB = __shfl_xor(a1B, mask, 64);
            float oC = __shfl_xor(a1C, mask, 64);
            float nm = fmaxf(m1s, om);
            float w1 = exp2f_(m1s - nm);
            float w2 = exp2f_(om - nm);
            sum1 = sum1 * w1 + os * w2;
            a1A = a1A * w1 + oA * w2;
            a1B = a1B * w1 + oB * w2;
            a1C = a1C * w1 + oC * w2;
            m1s = nm;
        }
    }

    if (q == 0) {
        size_t pbase = (size_t)(b * SPLIT + chunk) * 5 * NPIX;
        int n0 = n_base + c;
        partials[pbase + 0 * NPIX + n0] = m0s;
        partials[pbase + 1 * NPIX + n0] = sum0;
        partials[pbase + 2 * NPIX + n0] = a0A;
        partials[pbase + 3 * NPIX + n0] = a0B;
        partials[pbase + 4 * NPIX + n0] = a0C;
        int n1 = n_base + 16 + c;
        partials[pbase + 0 * NPIX + n1] = m1s;
        partials[pbase + 1 * NPIX + n1] = sum1;
        partials[pbase + 2 * NPIX + n1] = a1A;
        partials[pbase + 3 * NPIX + n1] = a1B;
        partials[pbase + 4 * NPIX + n1] = a1C;
    }
}

// ---------------- Kernel 3: merge chunks, diff, L1+Huber, reduce ----------------
__global__ void loss_kernel(const float* __restrict__ partials,
                            const float* __restrict__ lab0ws,
                            float* __restrict__ out)
{
    int gid = blockIdx.x * blockDim.x + threadIdx.x;   // 0..8191
    int b = gid >> 12;
    int n = gid & (NPIX - 1);

    float M = -INFINITY;
    #pragma unroll
    for (int ch = 0; ch < SPLIT; ++ch)
        M = fmaxf(M, partials[((size_t)(b * SPLIT + ch) * 5 + 0) * NPIX + n]);
    float S = 0.0f, A0 = 0.0f, A1 = 0.0f, A2 = 0.0f;
    #pragma unroll
    for (int ch = 0; ch < SPLIT; ++ch) {
        size_t base = (size_t)(b * SPLIT + ch) * 5 * NPIX + n;
        float w = exp2f_(partials[base + 0 * NPIX] - M);
        S  += partials[base + 1 * NPIX] * w;
        A0 += partials[base + 2 * NPIX] * w;
        A1 += partials[base + 3 * NPIX] * w;
        A2 += partials[base + 4 * NPIX] * w;
    }
    float inv_s = 1.0f / S;
    float d0 = A0 * inv_s - lab0ws[(size_t)(b * 3 + 0) * NPIX + n];
    float d1 = A1 * inv_s - lab0ws[(size_t)(b * 3 + 1) * NPIX + n];
    float d2 = A2 * inv_s - lab0ws[(size_t)(b * 3 + 2) * NPIX + n];

    float val = 0.0f;
    #pragma unroll
    for (int cc = 0; cc < 3; ++cc) {
        float d = (cc == 0) ? d0 : (cc == 1) ? d1 : d2;
        float ad = fabsf(d);
        float hub = (ad < 1.0f) ? 0.5f * ad * ad : ad - 0.5f;
        val += ad + hub;
    }

    #pragma unroll
    for (int off = 32; off > 0; off >>= 1)
        val += __shfl_down(val, off);

    __shared__ float wsum[4];
    int lane = threadIdx.x & 63;
    int wave = threadIdx.x >> 6;
    if (lane == 0) wsum[wave] = val;
    __syncthreads();
    if (threadIdx.x == 0) {
        float s = wsum[0] + wsum[1] + wsum[2] + wsum[3];
        atomicAdd(out, s * (1.0f / 8192.0f));
    }
}

// ---------------- launcher ----------------
extern "C" void kernel_launch(void* const* d_in, const int* in_sizes, int n_in,
                              void* d_out, int out_size, void* d_ws, size_t ws_size,
                              hipStream_t stream) {
    const float* rgb0  = (const float*)d_in[0];
    const float* rgb1  = (const float*)d_in[1];
    const float* feat0 = (const float*)d_in[2];
    const float* feat1 = (const float*)d_in[3];
    float* out = (float*)d_out;
    float* ws  = (float*)d_ws;

    float* lab0 = ws;                         // 24576 floats
    float* lab1 = ws + 24576;                 // 24576 floats
    float* partials = ws + 49152;             // 2*16*5*4096 = 655360 floats
    short* f0t = (short*)(ws + 49152 + 655360);
    short* f1t = f0t + (size_t)BATCH * NPIX * FDIM;

    prep_kernel<<<320, 256, 0, stream>>>(rgb0, rgb1, feat0, feat1, lab0, lab1, f0t, f1t, out);

    int attn_grid = BATCH * SPLIT * 32;       // 1024 blocks x 256 thr (4 waves of 32 n-rows)
    attn_kernel<<<attn_grid, 256, 0, stream>>>(f0t, f1t, lab1, partials);

    loss_kernel<<<(BATCH * NPIX) / 256, 256, 0, stream>>>(partials, lab0, out);
}

// Round 6
// 88.800 us; speedup vs baseline: 1.2007x; 1.0548x over previous
//
#include <hip/hip_runtime.h>
#include <math.h>

#define NPIX   4096
#define FDIM   64
#define BATCH  2
#define SPLIT  16
#define CHUNK  (NPIX / SPLIT)      // 256
#define NTILE  (CHUNK / 16)        // 16 m-tiles of 16

typedef __attribute__((ext_vector_type(8))) short short8;
typedef __attribute__((ext_vector_type(4))) float floatx4;

__device__ __forceinline__ float exp2f_(float x) { return __builtin_amdgcn_exp2f(x); }

// round-to-nearest-even fp32 -> bf16
__device__ __forceinline__ short f2bf(float x) {
    union { float f; unsigned u; } c; c.f = x;
    unsigned r = (c.u + 0x7FFFu + ((c.u >> 16) & 1u)) >> 16;
    return (short)r;
}

// ---------------- LAB helpers ----------------
__device__ __forceinline__ float gamma_expand(float u) {
    return u > 0.04045f ? powf((u + 0.055f) * (1.0f / 1.055f), 2.4f)
                        : u * (1.0f / 12.92f);
}
__device__ __forceinline__ float lab_f(float t) {
    return t > 0.008856f ? cbrtf(t) : 7.787f * t + (16.0f / 116.0f);
}

// ---------------- Kernel 1: prep = feat transpose->bf16 (blocks 0..255) + LAB (blocks 256..319) ----
// f0t/f1t: [b][n][f] bf16; f0t pre-scaled by log2(e)/0.07 (logits in log2 space).
__global__ __launch_bounds__(256) void prep_kernel(
    const float* __restrict__ rgb0, const float* __restrict__ rgb1,
    const float* __restrict__ feat0, const float* __restrict__ feat1,
    float* __restrict__ lab0, float* __restrict__ lab1,
    short* __restrict__ f0t, short* __restrict__ f1t,
    float* __restrict__ out)
{
    int bid = blockIdx.x;
    int tid = threadIdx.x;

    if (bid < 256) {
        __shared__ short Tsm[64 * 72];
        int pair = bid >> 6;            // 0..3
        int tensor = pair >> 1;         // 0: f0, 1: f1
        int bb = pair & 1;
        int n0 = (bid & 63) * 64;
        const float* src = (tensor ? feat1 : feat0) + (size_t)bb * FDIM * NPIX;
        short* dst = (tensor ? f1t : f0t) + (size_t)bb * NPIX * FDIM;
        float scale = tensor ? 1.0f : (1.442695040888963f / 0.07f);

        int f = tid >> 2;
        int slot = tid & 3;
        #pragma unroll
        for (int i = 0; i < 4; ++i) {
            int col4 = slot * 4 + i;
            int noff = col4 * 4;
            float4 v = *(const float4*)&src[(size_t)f * NPIX + n0 + noff];
            Tsm[(noff + 0) * 72 + f] = f2bf(v.x * scale);
            Tsm[(noff + 1) * 72 + f] = f2bf(v.y * scale);
            Tsm[(noff + 2) * 72 + f] = f2bf(v.z * scale);
            Tsm[(noff + 3) * 72 + f] = f2bf(v.w * scale);
        }
        __syncthreads();
        #pragma unroll
        for (int i = 0; i < 2; ++i) {
            int idx = i * 256 + tid;
            int row = idx >> 3, ch = idx & 7;
            *(short8*)&dst[(size_t)(n0 + row) * FDIM + ch * 8] =
                *(const short8*)&Tsm[row * 72 + ch * 8];
        }
        return;
    }

    if (bid == 256 && tid == 0) out[0] = 0.0f;   // zero-init for loss atomicAdd

    // LAB branch
    int gid = (bid - 256) * 256 + tid;     // 0 .. 16383
    int img = gid / (BATCH * NPIX);
    int rem = gid - img * (BATCH * NPIX);
    int b = rem / NPIX;
    int n = rem - b * NPIX;
    const float* rgb = img ? rgb1 : rgb0;
    float* lab = img ? lab1 : lab0;

    size_t i0 = (size_t)(b * 3 + 0) * NPIX + n;
    size_t i1 = (size_t)(b * 3 + 1) * NPIX + n;
    size_t i2 = (size_t)(b * 3 + 2) * NPIX + n;

    float r = gamma_expand(rgb[i0] + 0.5f);
    float g = gamma_expand(rgb[i1] + 0.5f);
    float bl = gamma_expand(rgb[i2] + 0.5f);

    float X = (0.412453f * r + 0.357580f * g + 0.180423f * bl) * (1.0f / 0.95047f);
    float Y = (0.212671f * r + 0.715160f * g + 0.072169f * bl);
    float Z = (0.019334f * r + 0.119193f * g + 0.950227f * bl) * (1.0f / 1.08883f);

    float fx = lab_f(X), fy = lab_f(Y), fz = lab_f(Z);
    float L = 116.0f * fy - 16.0f;
    float a = 500.0f * (fx - fy);
    float bb2 = 200.0f * (fy - fz);

    lab[i0] = (L - 50.0f) * (1.0f / 100.0f);
    lab[i1] = a * (1.0f / 110.0f);
    lab[i2] = bb2 * (1.0f / 110.0f);
}

// ---------------- Kernel 2: MFMA attn, 4-deep X register ring ----------------
// mfma(X=f1 rows m, Y=f0 rows n): D[row=q*4+r <-> m][col=lane&15 <-> n]  (bench-verified R5).
// Labels for the whole m-chunk staged once in LDS (one barrier); X fragments kept 4 tiles
// in flight in a register ring so first-use L3 latency (~500 cyc) is fully covered.
__global__ __launch_bounds__(256, 4) void attn_kernel(
    const short* __restrict__ f0t, const short* __restrict__ f1t,
    const float* __restrict__ lab1ws, float* __restrict__ partials)
{
    __shared__ float Lt[3 * CHUNK];        // 768 floats

    int bid = blockIdx.x;
    int rowblk = bid & 31;                 // 32 rowblocks of 128 n-rows
    int chunk = (bid >> 5) & (SPLIT - 1);
    int b = bid >> 9;
    int tid = threadIdx.x;
    int w = tid >> 6;
    int l = tid & 63;
    int c = l & 15;
    int q = l >> 4;

    int n_base = rowblk * 128 + w * 32;    // this wave: n_base..+15 (g0), +16..+31 (g1)
    int m_base = chunk * CHUNK;

    // stage labels for the whole m-chunk (3 x 256 floats)
    if (tid < 192) {
        int cc = tid >> 6;
        int m4 = tid & 63;
        *(float4*)&Lt[cc * CHUNK + m4 * 4] =
            *(const float4*)&lab1ws[(size_t)(b * 3 + cc) * NPIX + m_base + m4 * 4];
    }

    // Y fragments (f0, n-rows), two groups
    const short8* yp0 = (const short8*)(f0t + ((size_t)b * NPIX + n_base + c) * FDIM + q * 8);
    short8 y0a = yp0[0], y0b = yp0[4];
    const short8* yp1 = (const short8*)(f0t + ((size_t)b * NPIX + n_base + 16 + c) * FDIM + q * 8);
    short8 y1a = yp1[0], y1b = yp1[4];

    // X base (f1, m-rows): lane c -> row m_base + c; tile t advances 16 rows = 128 short8
    const short8* xbase = (const short8*)(f1t + ((size_t)b * NPIX + m_base + c) * FDIM + q * 8);

    // prime 4-deep ring
    short8 xa_r[4], xb_r[4];
    #pragma unroll
    for (int i = 0; i < 4; ++i) {
        xa_r[i] = xbase[(size_t)i * 128];
        xb_r[i] = xbase[(size_t)i * 128 + 4];
    }

    __syncthreads();

    float m0s = -INFINITY, sum0 = 0.0f, a0A = 0.0f, a0B = 0.0f, a0C = 0.0f;
    float m1s = -INFINITY, sum1 = 0.0f, a1A = 0.0f, a1B = 0.0f, a1C = 0.0f;

    for (int tb = 0; tb < NTILE; tb += 4) {
        #pragma unroll
        for (int i = 0; i < 4; ++i) {
            int t = tb + i;

            floatx4 z = (floatx4)(0.0f);
            floatx4 acc0 = __builtin_amdgcn_mfma_f32_16x16x32_bf16(xa_r[i], y0a, z, 0, 0, 0);
            acc0 = __builtin_amdgcn_mfma_f32_16x16x32_bf16(xb_r[i], y0b, acc0, 0, 0, 0);
            floatx4 acc1 = __builtin_amdgcn_mfma_f32_16x16x32_bf16(xa_r[i], y1a, z, 0, 0, 0);
            acc1 = __builtin_amdgcn_mfma_f32_16x16x32_bf16(xb_r[i], y1b, acc1, 0, 0, 0);

            // refill ring slot i with tile t+4 (loads fly while we do softmax)
            if (t + 4 < NTILE) {
                xa_r[i] = xbase[(size_t)(t + 4) * 128];
                xb_r[i] = xbase[(size_t)(t + 4) * 128 + 4];
            }

            // labels for this tile: m = t*16 + q*4 + j  (broadcast within quad)
            float4 lA = *(const float4*)&Lt[0 * CHUNK + t * 16 + q * 4];
            float4 lB = *(const float4*)&Lt[1 * CHUNK + t * 16 + q * 4];
            float4 lC = *(const float4*)&Lt[2 * CHUNK + t * 16 + q * 4];

            // state 0 update (n-group 0)
            {
                float L0 = acc0[0], L1 = acc0[1], L2 = acc0[2], L3 = acc0[3];
                float tmax = fmaxf(fmaxf(L0, L1), fmaxf(L2, L3));
                float nm = fmaxf(m0s, tmax);
                float sc = exp2f_(m0s - nm);
                float p0 = exp2f_(L0 - nm);
                float p1 = exp2f_(L1 - nm);
                float p2 = exp2f_(L2 - nm);
                float p3 = exp2f_(L3 - nm);
                sum0 = sum0 * sc + ((p0 + p1) + (p2 + p3));
                a0A = a0A * sc + ((p0 * lA.x + p1 * lA.y) + (p2 * lA.z + p3 * lA.w));
                a0B = a0B * sc + ((p0 * lB.x + p1 * lB.y) + (p2 * lB.z + p3 * lB.w));
                a0C = a0C * sc + ((p0 * lC.x + p1 * lC.y) + (p2 * lC.z + p3 * lC.w));
                m0s = nm;
            }
            // state 1 update (n-group 1)
            {
                float L0 = acc1[0], L1 = acc1[1], L2 = acc1[2], L3 = acc1[3];
                float tmax = fmaxf(fmaxf(L0, L1), fmaxf(L2, L3));
                float nm = fmaxf(m1s, tmax);
                float sc = exp2f_(m1s - nm);
                float p0 = exp2f_(L0 - nm);
                float p1 = exp2f_(L1 - nm);
                float p2 = exp2f_(L2 - nm);
                float p3 = exp2f_(L3 - nm);
                sum1 = sum1 * sc + ((p0 + p1) + (p2 + p3));
                a1A = a1A * sc + ((p0 * lA.x + p1 * lA.y) + (p2 * lA.z + p3 * lA.w));
                a1B = a1B * sc + ((p0 * lB.x + p1 * lB.y) + (p2 * lB.z + p3 * lB.w));
                a1C = a1C * sc + ((p0 * lC.x + p1 * lC.y) + (p2 * lC.z + p3 * lC.w));
                m1s = nm;
            }
        }
    }

    // butterfly merge across q (lane bits 4-5): 2 steps
    #pragma unroll
    for (int mask = 16; mask <= 32; mask <<= 1) {
        {
            float om = __shfl_xor(m0s, mask, 64);
            float os = __shfl_xor(sum0, mask, 64);
            float oA = __shfl_xor(a0A, mask, 64);
            float oB = __shfl_xor(a0B, mask, 64);
            float oC = __shfl_xor(a0C, mask, 64);
            float nm = fmaxf(m0s, om);
            float w1 = exp2f_(m0s - nm);
            float w2 = exp2f_(om - nm);
            sum0 = sum0 * w1 + os * w2;
            a0A = a0A * w1 + oA * w2;
            a0B = a0B * w1 + oB * w2;
            a0C = a0C * w1 + oC * w2;
            m0s = nm;
        }
        {
            float om = __shfl_xor(m1s, mask, 64);
            float os = __shfl_xor(sum1, mask, 64);
            float oA = __shfl_xor(a1A, mask, 64);
            float oB = __shfl_xor(a1B, mask, 64);
            float oC = __shfl_xor(a1C, mask, 64);
            float nm = fmaxf(m1s, om);
            float w1 = exp2f_(m1s - nm);
            float w2 = exp2f_(om - nm);
            sum1 = sum1 * w1 + os * w2;
            a1A = a1A * w1 + oA * w2;
            a1B = a1B * w1 + oB * w2;
            a1C = a1C * w1 + oC * w2;
            m1s = nm;
        }
    }

    if (q == 0) {
        size_t pbase = (size_t)(b * SPLIT + chunk) * 5 * NPIX;
        int n0 = n_base + c;
        partials[pbase + 0 * NPIX + n0] = m0s;
        partials[pbase + 1 * NPIX + n0] = sum0;
        partials[pbase + 2 * NPIX + n0] = a0A;
        partials[pbase + 3 * NPIX + n0] = a0B;
        partials[pbase + 4 * NPIX + n0] = a0C;
        int n1 = n_base + 16 + c;
        partials[pbase + 0 * NPIX + n1] = m1s;
        partials[pbase + 1 * NPIX + n1] = sum1;
        partials[pbase + 2 * NPIX + n1] = a1A;
        partials[pbase + 3 * NPIX + n1] = a1B;
        partials[pbase + 4 * NPIX + n1] = a1C;
    }
}

// ---------------- Kernel 3: merge chunks, diff, L1+Huber, reduce ----------------
__global__ void loss_kernel(const float* __restrict__ partials,
                            const float* __restrict__ lab0ws,
                            float* __restrict__ out)
{
    int gid = blockIdx.x * blockDim.x + threadIdx.x;   // 0..8191
    int b = gid >> 12;
    int n = gid & (NPIX - 1);

    float M = -INFINITY;
    #pragma unroll
    for (int ch = 0; ch < SPLIT; ++ch)
        M = fmaxf(M, partials[((size_t)(b * SPLIT + ch) * 5 + 0) * NPIX + n]);
    float S = 0.0f, A0 = 0.0f, A1 = 0.0f, A2 = 0.0f;
    #pragma unroll
    for (int ch = 0; ch < SPLIT; ++ch) {
        size_t base = (size_t)(b * SPLIT + ch) * 5 * NPIX + n;
        float w = exp2f_(partials[base + 0 * NPIX] - M);
        S  += partials[base + 1 * NPIX] * w;
        A0 += partials[base + 2 * NPIX] * w;
        A1 += partials[base + 3 * NPIX] * w;
        A2 += partials[base + 4 * NPIX] * w;
    }
    float inv_s = 1.0f / S;
    float d0 = A0 * inv_s - lab0ws[(size_t)(b * 3 + 0) * NPIX + n];
    float d1 = A1 * inv_s - lab0ws[(size_t)(b * 3 + 1) * NPIX + n];
    float d2 = A2 * inv_s - lab0ws[(size_t)(b * 3 + 2) * NPIX + n];

    float val = 0.0f;
    #pragma unroll
    for (int cc = 0; cc < 3; ++cc) {
        float d = (cc == 0) ? d0 : (cc == 1) ? d1 : d2;
        float ad = fabsf(d);
        float hub = (ad < 1.0f) ? 0.5f * ad * ad : ad - 0.5f;
        val += ad + hub;
    }

    #pragma unroll
    for (int off = 32; off > 0; off >>= 1)
        val += __shfl_down(val, off);

    __shared__ float wsum[4];
    int lane = threadIdx.x & 63;
    int wave = threadIdx.x >> 6;
    if (lane == 0) wsum[wave] = val;
    __syncthreads();
    if (threadIdx.x == 0) {
        float s = wsum[0] + wsum[1] + wsum[2] + wsum[3];
        atomicAdd(out, s * (1.0f / 8192.0f));
    }
}

// ---------------- launcher ----------------
extern "C" void kernel_launch(void* const* d_in, const int* in_sizes, int n_in,
                              void* d_out, int out_size, void* d_ws, size_t ws_size,
                              hipStream_t stream) {
    const float* rgb0  = (const float*)d_in[0];
    const float* rgb1  = (const float*)d_in[1];
    const float* feat0 = (const float*)d_in[2];
    const float* feat1 = (const float*)d_in[3];
    float* out = (float*)d_out;
    float* ws  = (float*)d_ws;

    float* lab0 = ws;                         // 24576 floats
    float* lab1 = ws + 24576;                 // 24576 floats
    float* partials = ws + 49152;             // 2*16*5*4096 = 655360 floats
    short* f0t = (short*)(ws + 49152 + 655360);
    short* f1t = f0t + (size_t)BATCH * NPIX * FDIM;

    prep_kernel<<<320, 256, 0, stream>>>(rgb0, rgb1, feat0, feat1, lab0, lab1, f0t, f1t, out);

    int attn_grid = BATCH * SPLIT * 32;       // 1024 blocks x 256 thr (4 waves of 32 n-rows)
    attn_kernel<<<attn_grid, 256, 0, stream>>>(f0t, f1t, lab1, partials);

    loss_kernel<<<(BATCH * NPIX) / 256, 256, 0, stream>>>(partials, lab0, out);
}

// Round 7
// 88.597 us; speedup vs baseline: 1.2035x; 1.0023x over previous
//
#include <hip/hip_runtime.h>
#include <math.h>

#define NPIX   4096
#define FDIM   64
#define BATCH  2
#define SPLIT  16
#define CHUNK  256                 // m-cols per block
#define BLKN   128                 // n-rows per block
#define NTILE  (CHUNK / 16)        // 16 m-tiles
#define PITCH  72                  // shorts per LDS row (64 + 8 pad, 16B-aligned rows)

typedef __attribute__((ext_vector_type(8))) short short8;
typedef __attribute__((ext_vector_type(4))) float floatx4;

__device__ __forceinline__ float exp2f_(float x) { return __builtin_amdgcn_exp2f(x); }

// round-to-nearest-even fp32 -> bf16 (returns raw u16)
__device__ __forceinline__ unsigned short f2bf(float x) {
    union { float f; unsigned u; } c; c.f = x;
    unsigned r = (c.u + 0x7FFFu + ((c.u >> 16) & 1u)) >> 16;
    return (unsigned short)r;
}
__device__ __forceinline__ unsigned pk_bf(float lo, float hi) {
    return (unsigned)f2bf(lo) | ((unsigned)f2bf(hi) << 16);
}

// ---------------- LAB helpers ----------------
__device__ __forceinline__ float gamma_expand(float u) {
    return u > 0.04045f ? powf((u + 0.055f) * (1.0f / 1.055f), 2.4f)
                        : u * (1.0f / 12.92f);
}
__device__ __forceinline__ float lab_f(float t) {
    return t > 0.008856f ? cbrtf(t) : 7.787f * t + (16.0f / 116.0f);
}
// rgb (3 strided planes at index idx) -> normalized LAB triplet
__device__ __forceinline__ void rgb_to_lab(const float* rgb, size_t plane, size_t idx,
                                           float& o0, float& o1, float& o2) {
    float r  = gamma_expand(rgb[idx] + 0.5f);
    float g  = gamma_expand(rgb[plane + idx] + 0.5f);
    float bl = gamma_expand(rgb[2 * plane + idx] + 0.5f);
    float X = (0.412453f * r + 0.357580f * g + 0.180423f * bl) * (1.0f / 0.95047f);
    float Y = (0.212671f * r + 0.715160f * g + 0.072169f * bl);
    float Z = (0.019334f * r + 0.119193f * g + 0.950227f * bl) * (1.0f / 1.08883f);
    float fx = lab_f(X), fy = lab_f(Y), fz = lab_f(Z);
    o0 = (116.0f * fy - 16.0f - 50.0f) * (1.0f / 100.0f);
    o1 = (500.0f * (fx - fy)) * (1.0f / 110.0f);
    o2 = (200.0f * (fy - fz)) * (1.0f / 110.0f);
}

// ---------------- Kernel 1: fully-fused attention ----------------
// Per block: stage Y (128 f0-rows, scaled, bf16) into LDS, pull fragments to regs,
// overwrite same buffer with X (256 f1-rows), compute chunk labels from rgb1 in-block.
// Main loop = LDS reads + MFMA + online softmax only (no global, no barriers).
// mfma(X, Y): D[row=q*4+r <-> m][col=lane&15 <-> n]  (bench-verified R5/R6).
__global__ __launch_bounds__(256, 4) void attn_kernel(
    const float* __restrict__ feat0, const float* __restrict__ feat1,
    const float* __restrict__ rgb1, float* __restrict__ partials,
    float* __restrict__ out)
{
    __shared__ short Sm[CHUNK * PITCH];   // 36,864 B; Y phase uses first 128 rows
    __shared__ float Lt[3 * CHUNK];       // 3 KB

    int bid = blockIdx.x;
    int rowblk = bid & 31;                // 32 rowblocks of 128 n
    int chunk = (bid >> 5) & (SPLIT - 1);
    int b = bid >> 9;
    int n_blk = rowblk * BLKN;
    int m_base = chunk * CHUNK;

    int tid = threadIdx.x;
    int w = tid >> 6;
    int l = tid & 63;
    int c = l & 15;
    int q = l >> 4;

    if (bid == 0 && tid == 0) out[0] = 0.0f;   // zero before loss kernel's atomics

    unsigned* SmU = (unsigned*)Sm;
    int p = tid >> 3;                     // f-pair 0..31
    int sub = tid & 7;

    // ---- stage Y: f0 rows n_blk..+127, scaled by log2(e)/0.07, [n][PITCH] bf16 ----
    {
        const float s = 1.442695040888963f / 0.07f;
        const float* r0 = feat0 + ((size_t)b * FDIM + 2 * p) * NPIX + n_blk;
        const float* r1 = r0 + NPIX;
        #pragma unroll
        for (int i = 0; i < BLKN / 32; ++i) {          // 4
            int n0 = i * 32 + sub * 4;
            float4 vA = *(const float4*)&r0[n0];
            float4 vB = *(const float4*)&r1[n0];
            SmU[(n0 + 0) * (PITCH / 2) + p] = pk_bf(vA.x * s, vB.x * s);
            SmU[(n0 + 1) * (PITCH / 2) + p] = pk_bf(vA.y * s, vB.y * s);
            SmU[(n0 + 2) * (PITCH / 2) + p] = pk_bf(vA.z * s, vB.z * s);
            SmU[(n0 + 3) * (PITCH / 2) + p] = pk_bf(vA.w * s, vB.w * s);
        }
    }
    __syncthreads();

    // ---- pull Y fragments to registers (rows w*32+c and w*32+16+c, k-halves) ----
    int nl = w * 32 + c;
    short8 y0a = *(const short8*)&Sm[nl * PITCH + q * 8];
    short8 y0b = *(const short8*)&Sm[nl * PITCH + 32 + q * 8];
    short8 y1a = *(const short8*)&Sm[(nl + 16) * PITCH + q * 8];
    short8 y1b = *(const short8*)&Sm[(nl + 16) * PITCH + 32 + q * 8];
    __syncthreads();   // all y-frag reads done before X overwrites the buffer

    // ---- stage X: f1 rows m_base..+255, [m][PITCH] bf16 ----
    {
        const float* r0 = feat1 + ((size_t)b * FDIM + 2 * p) * NPIX + m_base;
        const float* r1 = r0 + NPIX;
        #pragma unroll
        for (int i = 0; i < CHUNK / 32; ++i) {         // 8
            int m0 = i * 32 + sub * 4;
            float4 vA = *(const float4*)&r0[m0];
            float4 vB = *(const float4*)&r1[m0];
            SmU[(m0 + 0) * (PITCH / 2) + p] = pk_bf(vA.x, vB.x);
            SmU[(m0 + 1) * (PITCH / 2) + p] = pk_bf(vA.y, vB.y);
            SmU[(m0 + 2) * (PITCH / 2) + p] = pk_bf(vA.z, vB.z);
            SmU[(m0 + 3) * (PITCH / 2) + p] = pk_bf(vA.w, vB.w);
        }
    }
    // ---- labels for the chunk, computed in-block (1 pixel/thread) ----
    {
        float o0, o1, o2;
        rgb_to_lab(rgb1 + (size_t)b * 3 * NPIX, NPIX, (size_t)(m_base + tid), o0, o1, o2);
        Lt[0 * CHUNK + tid] = o0;
        Lt[1 * CHUNK + tid] = o1;
        Lt[2 * CHUNK + tid] = o2;
    }
    __syncthreads();

    // ---- main loop: LDS-only ----
    float m0s = -INFINITY, sum0 = 0.0f, a0A = 0.0f, a0B = 0.0f, a0C = 0.0f;
    float m1s = -INFINITY, sum1 = 0.0f, a1A = 0.0f, a1B = 0.0f, a1C = 0.0f;

    #pragma unroll 4
    for (int t = 0; t < NTILE; ++t) {
        const short* xr = &Sm[(t * 16 + c) * PITCH + q * 8];
        short8 xa = *(const short8*)xr;
        short8 xb = *(const short8*)(xr + 32);

        floatx4 z = (floatx4)(0.0f);
        floatx4 acc0 = __builtin_amdgcn_mfma_f32_16x16x32_bf16(xa, y0a, z, 0, 0, 0);
        acc0 = __builtin_amdgcn_mfma_f32_16x16x32_bf16(xb, y0b, acc0, 0, 0, 0);
        floatx4 acc1 = __builtin_amdgcn_mfma_f32_16x16x32_bf16(xa, y1a, z, 0, 0, 0);
        acc1 = __builtin_amdgcn_mfma_f32_16x16x32_bf16(xb, y1b, acc1, 0, 0, 0);

        float4 lA = *(const float4*)&Lt[0 * CHUNK + t * 16 + q * 4];
        float4 lB = *(const float4*)&Lt[1 * CHUNK + t * 16 + q * 4];
        float4 lC = *(const float4*)&Lt[2 * CHUNK + t * 16 + q * 4];

        {   // n-group 0
            float L0 = acc0[0], L1 = acc0[1], L2 = acc0[2], L3 = acc0[3];
            float tmax = fmaxf(fmaxf(L0, L1), fmaxf(L2, L3));
            float nm = fmaxf(m0s, tmax);
            float sc = exp2f_(m0s - nm);
            float p0 = exp2f_(L0 - nm);
            float p1 = exp2f_(L1 - nm);
            float p2 = exp2f_(L2 - nm);
            float p3 = exp2f_(L3 - nm);
            sum0 = sum0 * sc + ((p0 + p1) + (p2 + p3));
            a0A = a0A * sc + ((p0 * lA.x + p1 * lA.y) + (p2 * lA.z + p3 * lA.w));
            a0B = a0B * sc + ((p0 * lB.x + p1 * lB.y) + (p2 * lB.z + p3 * lB.w));
            a0C = a0C * sc + ((p0 * lC.x + p1 * lC.y) + (p2 * lC.z + p3 * lC.w));
            m0s = nm;
        }
        {   // n-group 1
            float L0 = acc1[0], L1 = acc1[1], L2 = acc1[2], L3 = acc1[3];
            float tmax = fmaxf(fmaxf(L0, L1), fmaxf(L2, L3));
            float nm = fmaxf(m1s, tmax);
            float sc = exp2f_(m1s - nm);
            float p0 = exp2f_(L0 - nm);
            float p1 = exp2f_(L1 - nm);
            float p2 = exp2f_(L2 - nm);
            float p3 = exp2f_(L3 - nm);
            sum1 = sum1 * sc + ((p0 + p1) + (p2 + p3));
            a1A = a1A * sc + ((p0 * lA.x + p1 * lA.y) + (p2 * lA.z + p3 * lA.w));
            a1B = a1B * sc + ((p0 * lB.x + p1 * lB.y) + (p2 * lB.z + p3 * lB.w));
            a1C = a1C * sc + ((p0 * lC.x + p1 * lC.y) + (p2 * lC.z + p3 * lC.w));
            m1s = nm;
        }
    }

    // ---- butterfly merge across q (lane bits 4-5) ----
    #pragma unroll
    for (int mask = 16; mask <= 32; mask <<= 1) {
        {
            float om = __shfl_xor(m0s, mask, 64);
            float os = __shfl_xor(sum0, mask, 64);
            float oA = __shfl_xor(a0A, mask, 64);
            float oB = __shfl_xor(a0B, mask, 64);
            float oC = __shfl_xor(a0C, mask, 64);
            float nm = fmaxf(m0s, om);
            float w1 = exp2f_(m0s - nm);
            float w2 = exp2f_(om - nm);
            sum0 = sum0 * w1 + os * w2;
            a0A = a0A * w1 + oA * w2;
            a0B = a0B * w1 + oB * w2;
            a0C = a0C * w1 + oC * w2;
            m0s = nm;
        }
        {
            float om = __shfl_xor(m1s, mask, 64);
            float os = __shfl_xor(sum1, mask, 64);
            float oA = __shfl_xor(a1A, mask, 64);
            float oB = __shfl_xor(a1B, mask, 64);
            float oC = __shfl_xor(a1C, mask, 64);
            float nm = fmaxf(m1s, om);
            float w1 = exp2f_(m1s - nm);
            float w2 = exp2f_(om - nm);
            sum1 = sum1 * w1 + os * w2;
            a1A = a1A * w1 + oA * w2;
            a1B = a1B * w1 + oB * w2;
            a1C = a1C * w1 + oC * w2;
            m1s = nm;
        }
    }

    if (q == 0) {
        size_t pbase = (size_t)(b * SPLIT + chunk) * 5 * NPIX;
        int n0 = n_blk + w * 32 + c;
        partials[pbase + 0 * NPIX + n0] = m0s;
        partials[pbase + 1 * NPIX + n0] = sum0;
        partials[pbase + 2 * NPIX + n0] = a0A;
        partials[pbase + 3 * NPIX + n0] = a0B;
        partials[pbase + 4 * NPIX + n0] = a0C;
        int n1 = n0 + 16;
        partials[pbase + 0 * NPIX + n1] = m1s;
        partials[pbase + 1 * NPIX + n1] = sum1;
        partials[pbase + 2 * NPIX + n1] = a1A;
        partials[pbase + 3 * NPIX + n1] = a1B;
        partials[pbase + 4 * NPIX + n1] = a1C;
    }
}

// ---------------- Kernel 2: merge chunks + lab0 inline + L1+Huber reduce ----------------
__global__ void loss_kernel(const float* __restrict__ partials,
                            const float* __restrict__ rgb0,
                            float* __restrict__ out)
{
    int gid = blockIdx.x * blockDim.x + threadIdx.x;   // 0..8191
    int b = gid >> 12;
    int n = gid & (NPIX - 1);

    float M = -INFINITY;
    #pragma unroll
    for (int ch = 0; ch < SPLIT; ++ch)
        M = fmaxf(M, partials[((size_t)(b * SPLIT + ch) * 5 + 0) * NPIX + n]);
    float S = 0.0f, A0 = 0.0f, A1 = 0.0f, A2 = 0.0f;
    #pragma unroll
    for (int ch = 0; ch < SPLIT; ++ch) {
        size_t base = (size_t)(b * SPLIT + ch) * 5 * NPIX + n;
        float w = exp2f_(partials[base + 0 * NPIX] - M);
        S  += partials[base + 1 * NPIX] * w;
        A0 += partials[base + 2 * NPIX] * w;
        A1 += partials[base + 3 * NPIX] * w;
        A2 += partials[base + 4 * NPIX] * w;
    }
    float l0, l1, l2;
    rgb_to_lab(rgb0 + (size_t)b * 3 * NPIX, NPIX, (size_t)n, l0, l1, l2);

    float inv_s = 1.0f / S;
    float d0 = A0 * inv_s - l0;
    float d1 = A1 * inv_s - l1;
    float d2 = A2 * inv_s - l2;

    float val = 0.0f;
    #pragma unroll
    for (int cc = 0; cc < 3; ++cc) {
        float d = (cc == 0) ? d0 : (cc == 1) ? d1 : d2;
        float ad = fabsf(d);
        float hub = (ad < 1.0f) ? 0.5f * ad * ad : ad - 0.5f;
        val += ad + hub;
    }

    #pragma unroll
    for (int off = 32; off > 0; off >>= 1)
        val += __shfl_down(val, off);

    __shared__ float wsum[4];
    int lane = threadIdx.x & 63;
    int wave = threadIdx.x >> 6;
    if (lane == 0) wsum[wave] = val;
    __syncthreads();
    if (threadIdx.x == 0) {
        float s = wsum[0] + wsum[1] + wsum[2] + wsum[3];
        atomicAdd(out, s * (1.0f / 8192.0f));
    }
}

// ---------------- launcher ----------------
extern "C" void kernel_launch(void* const* d_in, const int* in_sizes, int n_in,
                              void* d_out, int out_size, void* d_ws, size_t ws_size,
                              hipStream_t stream) {
    const float* rgb0  = (const float*)d_in[0];
    const float* rgb1  = (const float*)d_in[1];
    const float* feat0 = (const float*)d_in[2];
    const float* feat1 = (const float*)d_in[3];
    float* out = (float*)d_out;
    float* partials = (float*)d_ws;           // 2*16*5*4096 floats = 2.6 MB

    int attn_grid = BATCH * SPLIT * (NPIX / BLKN);   // 1024
    attn_kernel<<<attn_grid, 256, 0, stream>>>(feat0, feat1, rgb1, partials, out);

    loss_kernel<<<(BATCH * NPIX) / 256, 256, 0, stream>>>(partials, rgb0, out);
}

// Round 8
// 87.582 us; speedup vs baseline: 1.2174x; 1.0116x over previous
//
#include <hip/hip_runtime.h>
#include <math.h>

#define NPIX   4096
#define FDIM   64
#define BATCH  2
#define SPLIT  16
#define CHUNK  (NPIX / SPLIT)      // 256
#define NTILE  (CHUNK / 16)        // 16 m-tiles of 16
#define BLKN   256                 // n-rows per block (4 waves x 64)

typedef __attribute__((ext_vector_type(8))) short short8;
typedef __attribute__((ext_vector_type(4))) float floatx4;

__device__ __forceinline__ float exp2f_(float x) { return __builtin_amdgcn_exp2f(x); }

// round-to-nearest-even fp32 -> bf16
__device__ __forceinline__ short f2bf(float x) {
    union { float f; unsigned u; } c; c.f = x;
    unsigned r = (c.u + 0x7FFFu + ((c.u >> 16) & 1u)) >> 16;
    return (short)r;
}

// ---------------- LAB helpers ----------------
__device__ __forceinline__ float gamma_expand(float u) {
    return u > 0.04045f ? powf((u + 0.055f) * (1.0f / 1.055f), 2.4f)
                        : u * (1.0f / 12.92f);
}
__device__ __forceinline__ float lab_f(float t) {
    return t > 0.008856f ? cbrtf(t) : 7.787f * t + (16.0f / 116.0f);
}

// ---------------- Kernel 1: prep = feat transpose->bf16 (blocks 0..255) + LAB (blocks 256..319) ----
// f0t/f1t: [b][n][f] bf16; f0t pre-scaled by log2(e)/0.07 (logits in log2 space).
__global__ __launch_bounds__(256) void prep_kernel(
    const float* __restrict__ rgb0, const float* __restrict__ rgb1,
    const float* __restrict__ feat0, const float* __restrict__ feat1,
    float* __restrict__ lab0, float* __restrict__ lab1,
    short* __restrict__ f0t, short* __restrict__ f1t,
    float* __restrict__ out)
{
    int bid = blockIdx.x;
    int tid = threadIdx.x;

    if (bid < 256) {
        __shared__ short Tsm[64 * 72];
        int pair = bid >> 6;            // 0..3
        int tensor = pair >> 1;         // 0: f0, 1: f1
        int bb = pair & 1;
        int n0 = (bid & 63) * 64;
        const float* src = (tensor ? feat1 : feat0) + (size_t)bb * FDIM * NPIX;
        short* dst = (tensor ? f1t : f0t) + (size_t)bb * NPIX * FDIM;
        float scale = tensor ? 1.0f : (1.442695040888963f / 0.07f);

        int f = tid >> 2;
        int slot = tid & 3;
        #pragma unroll
        for (int i = 0; i < 4; ++i) {
            int col4 = slot * 4 + i;
            int noff = col4 * 4;
            float4 v = *(const float4*)&src[(size_t)f * NPIX + n0 + noff];
            Tsm[(noff + 0) * 72 + f] = f2bf(v.x * scale);
            Tsm[(noff + 1) * 72 + f] = f2bf(v.y * scale);
            Tsm[(noff + 2) * 72 + f] = f2bf(v.z * scale);
            Tsm[(noff + 3) * 72 + f] = f2bf(v.w * scale);
        }
        __syncthreads();
        #pragma unroll
        for (int i = 0; i < 2; ++i) {
            int idx = i * 256 + tid;
            int row = idx >> 3, ch = idx & 7;
            *(short8*)&dst[(size_t)(n0 + row) * FDIM + ch * 8] =
                *(const short8*)&Tsm[row * 72 + ch * 8];
        }
        return;
    }

    if (bid == 256 && tid == 0) out[0] = 0.0f;   // zero-init for loss atomicAdd

    // LAB branch
    int gid = (bid - 256) * 256 + tid;     // 0 .. 16383
    int img = gid / (BATCH * NPIX);
    int rem = gid - img * (BATCH * NPIX);
    int b = rem / NPIX;
    int n = rem - b * NPIX;
    const float* rgb = img ? rgb1 : rgb0;
    float* lab = img ? lab1 : lab0;

    size_t i0 = (size_t)(b * 3 + 0) * NPIX + n;
    size_t i1 = (size_t)(b * 3 + 1) * NPIX + n;
    size_t i2 = (size_t)(b * 3 + 2) * NPIX + n;

    float r = gamma_expand(rgb[i0] + 0.5f);
    float g = gamma_expand(rgb[i1] + 0.5f);
    float bl = gamma_expand(rgb[i2] + 0.5f);

    float X = (0.412453f * r + 0.357580f * g + 0.180423f * bl) * (1.0f / 0.95047f);
    float Y = (0.212671f * r + 0.715160f * g + 0.072169f * bl);
    float Z = (0.019334f * r + 0.119193f * g + 0.950227f * bl) * (1.0f / 1.08883f);

    float fx = lab_f(X), fy = lab_f(Y), fz = lab_f(Z);
    float L = 116.0f * fy - 16.0f;
    float a = 500.0f * (fx - fy);
    float bb2 = 200.0f * (fy - fz);

    lab[i0] = (L - 50.0f) * (1.0f / 100.0f);
    lab[i1] = a * (1.0f / 110.0f);
    lab[i2] = bb2 * (1.0f / 110.0f);
}

// ---------------- Kernel 2: MFMA attn, 4 n-groups per wave, 4-deep X register ring ----------------
// mfma(X=f1 rows m, Y=f0 rows n): D[row=q*4+r <-> m][col=lane&15 <-> n]  (bench-verified R5-R7).
// Each wave covers 64 n-rows (4 Y-groups) -> 2x better X amortization + 4 independent
// MFMA/softmax chains per tile to hide ring-load latency. Labels staged once in LDS.
__global__ __launch_bounds__(256, 2) void attn_kernel(
    const short* __restrict__ f0t, const short* __restrict__ f1t,
    const float* __restrict__ lab1ws, float* __restrict__ partials)
{
    __shared__ float Lt[3 * CHUNK];        // 768 floats

    int bid = blockIdx.x;
    int rowblk = bid & 15;                 // 16 rowblocks of 256 n
    int chunk = (bid >> 4) & (SPLIT - 1);
    int b = bid >> 8;
    int tid = threadIdx.x;
    int w = tid >> 6;
    int l = tid & 63;
    int c = l & 15;
    int q = l >> 4;

    int n_base = rowblk * BLKN + w * 64;   // this wave: 4 groups of 16 starting here
    int m_base = chunk * CHUNK;

    // stage labels for the whole m-chunk (3 x 256 floats)
    if (tid < 192) {
        int cc = tid >> 6;
        int m4 = tid & 63;
        *(float4*)&Lt[cc * CHUNK + m4 * 4] =
            *(const float4*)&lab1ws[(size_t)(b * 3 + cc) * NPIX + m_base + m4 * 4];
    }

    // Y fragments (f0, n-rows), 4 groups
    short8 ya[4], yb[4];
    #pragma unroll
    for (int g = 0; g < 4; ++g) {
        const short8* yp = (const short8*)(f0t +
            ((size_t)b * NPIX + n_base + g * 16 + c) * FDIM + q * 8);
        ya[g] = yp[0];
        yb[g] = yp[4];
    }

    // X base (f1, m-rows): lane c -> row m_base + c; tile t advances 16 rows = 128 short8
    const short8* xbase = (const short8*)(f1t + ((size_t)b * NPIX + m_base + c) * FDIM + q * 8);

    // prime 4-deep ring
    short8 xa_r[4], xb_r[4];
    #pragma unroll
    for (int i = 0; i < 4; ++i) {
        xa_r[i] = xbase[(size_t)i * 128];
        xb_r[i] = xbase[(size_t)i * 128 + 4];
    }

    __syncthreads();

    float ms[4], sum[4], aA[4], aB[4], aC[4];
    #pragma unroll
    for (int g = 0; g < 4; ++g) {
        ms[g] = -INFINITY; sum[g] = 0.0f;
        aA[g] = 0.0f; aB[g] = 0.0f; aC[g] = 0.0f;
    }

    for (int tb = 0; tb < NTILE; tb += 4) {
        #pragma unroll
        for (int i = 0; i < 4; ++i) {
            int t = tb + i;

            floatx4 z = (floatx4)(0.0f);
            floatx4 acc[4];
            #pragma unroll
            for (int g = 0; g < 4; ++g) {
                acc[g] = __builtin_amdgcn_mfma_f32_16x16x32_bf16(xa_r[i], ya[g], z, 0, 0, 0);
                acc[g] = __builtin_amdgcn_mfma_f32_16x16x32_bf16(xb_r[i], yb[g], acc[g], 0, 0, 0);
            }

            // refill ring slot i with tile t+4 (loads fly during softmax below)
            if (t + 4 < NTILE) {
                xa_r[i] = xbase[(size_t)(t + 4) * 128];
                xb_r[i] = xbase[(size_t)(t + 4) * 128 + 4];
            }

            // labels for this tile: m = t*16 + q*4 + j (broadcast within quad, shared by groups)
            float4 lA = *(const float4*)&Lt[0 * CHUNK + t * 16 + q * 4];
            float4 lB = *(const float4*)&Lt[1 * CHUNK + t * 16 + q * 4];
            float4 lC = *(const float4*)&Lt[2 * CHUNK + t * 16 + q * 4];

            #pragma unroll
            for (int g = 0; g < 4; ++g) {
                float L0 = acc[g][0], L1 = acc[g][1], L2 = acc[g][2], L3 = acc[g][3];
                float tmax = fmaxf(fmaxf(L0, L1), fmaxf(L2, L3));
                float nm = fmaxf(ms[g], tmax);
                float sc = exp2f_(ms[g] - nm);
                float p0 = exp2f_(L0 - nm);
                float p1 = exp2f_(L1 - nm);
                float p2 = exp2f_(L2 - nm);
                float p3 = exp2f_(L3 - nm);
                sum[g] = sum[g] * sc + ((p0 + p1) + (p2 + p3));
                aA[g] = aA[g] * sc + ((p0 * lA.x + p1 * lA.y) + (p2 * lA.z + p3 * lA.w));
                aB[g] = aB[g] * sc + ((p0 * lB.x + p1 * lB.y) + (p2 * lB.z + p3 * lB.w));
                aC[g] = aC[g] * sc + ((p0 * lC.x + p1 * lC.y) + (p2 * lC.z + p3 * lC.w));
                ms[g] = nm;
            }
        }
    }

    // butterfly merge across q (lane bits 4-5): 2 steps, 4 groups
    #pragma unroll
    for (int mask = 16; mask <= 32; mask <<= 1) {
        #pragma unroll
        for (int g = 0; g < 4; ++g) {
            float om = __shfl_xor(ms[g], mask, 64);
            float os = __shfl_xor(sum[g], mask, 64);
            float oA = __shfl_xor(aA[g], mask, 64);
            float oB = __shfl_xor(aB[g], mask, 64);
            float oC = __shfl_xor(aC[g], mask, 64);
            float nm = fmaxf(ms[g], om);
            float w1 = exp2f_(ms[g] - nm);
            float w2 = exp2f_(om - nm);
            sum[g] = sum[g] * w1 + os * w2;
            aA[g] = aA[g] * w1 + oA * w2;
            aB[g] = aB[g] * w1 + oB * w2;
            aC[g] = aC[g] * w1 + oC * w2;
            ms[g] = nm;
        }
    }

    if (q == 0) {
        size_t pbase = (size_t)(b * SPLIT + chunk) * 5 * NPIX;
        #pragma unroll
        for (int g = 0; g < 4; ++g) {
            int n = n_base + g * 16 + c;
            partials[pbase + 0 * NPIX + n] = ms[g];
            partials[pbase + 1 * NPIX + n] = sum[g];
            partials[pbase + 2 * NPIX + n] = aA[g];
            partials[pbase + 3 * NPIX + n] = aB[g];
            partials[pbase + 4 * NPIX + n] = aC[g];
        }
    }
}

// ---------------- Kernel 3: merge chunks, diff, L1+Huber, reduce ----------------
__global__ void loss_kernel(const float* __restrict__ partials,
                            const float* __restrict__ lab0ws,
                            float* __restrict__ out)
{
    int gid = blockIdx.x * blockDim.x + threadIdx.x;   // 0..8191
    int b = gid >> 12;
    int n = gid & (NPIX - 1);

    float M = -INFINITY;
    #pragma unroll
    for (int ch = 0; ch < SPLIT; ++ch)
        M = fmaxf(M, partials[((size_t)(b * SPLIT + ch) * 5 + 0) * NPIX + n]);
    float S = 0.0f, A0 = 0.0f, A1 = 0.0f, A2 = 0.0f;
    #pragma unroll
    for (int ch = 0; ch < SPLIT; ++ch) {
        size_t base = (size_t)(b * SPLIT + ch) * 5 * NPIX + n;
        float w = exp2f_(partials[base + 0 * NPIX] - M);
        S  += partials[base + 1 * NPIX] * w;
        A0 += partials[base + 2 * NPIX] * w;
        A1 += partials[base + 3 * NPIX] * w;
        A2 += partials[base + 4 * NPIX] * w;
    }
    float inv_s = 1.0f / S;
    float d0 = A0 * inv_s - lab0ws[(size_t)(b * 3 + 0) * NPIX + n];
    float d1 = A1 * inv_s - lab0ws[(size_t)(b * 3 + 1) * NPIX + n];
    float d2 = A2 * inv_s - lab0ws[(size_t)(b * 3 + 2) * NPIX + n];

    float val = 0.0f;
    #pragma unroll
    for (int cc = 0; cc < 3; ++cc) {
        float d = (cc == 0) ? d0 : (cc == 1) ? d1 : d2;
        float ad = fabsf(d);
        float hub = (ad < 1.0f) ? 0.5f * ad * ad : ad - 0.5f;
        val += ad + hub;
    }

    #pragma unroll
    for (int off = 32; off > 0; off >>= 1)
        val += __shfl_down(val, off);

    __shared__ float wsum[4];
    int lane = threadIdx.x & 63;
    int wave = threadIdx.x >> 6;
    if (lane == 0) wsum[wave] = val;
    __syncthreads();
    if (threadIdx.x == 0) {
        float s = wsum[0] + wsum[1] + wsum[2] + wsum[3];
        atomicAdd(out, s * (1.0f / 8192.0f));
    }
}

// ---------------- launcher ----------------
extern "C" void kernel_launch(void* const* d_in, const int* in_sizes, int n_in,
                              void* d_out, int out_size, void* d_ws, size_t ws_size,
                              hipStream_t stream) {
    const float* rgb0  = (const float*)d_in[0];
    const float* rgb1  = (const float*)d_in[1];
    const float* feat0 = (const float*)d_in[2];
    const float* feat1 = (const float*)d_in[3];
    float* out = (float*)d_out;
    float* ws  = (float*)d_ws;

    float* lab0 = ws;                         // 24576 floats
    float* lab1 = ws + 24576;                 // 24576 floats
    float* partials = ws + 49152;             // 2*16*5*4096 = 655360 floats
    short* f0t = (short*)(ws + 49152 + 655360);
    short* f1t = f0t + (size_t)BATCH * NPIX * FDIM;

    prep_kernel<<<320, 256, 0, stream>>>(rgb0, rgb1, feat0, feat1, lab0, lab1, f0t, f1t, out);

    int attn_grid = BATCH * SPLIT * (NPIX / BLKN);   // 512
    attn_kernel<<<attn_grid, 256, 0, stream>>>(f0t, f1t, lab1, partials);

    loss_kernel<<<(BATCH * NPIX) / 256, 256, 0, stream>>>(partials, lab0, out);
}

// Round 9
// 83.370 us; speedup vs baseline: 1.2789x; 1.0505x over previous
//
#include <hip/hip_runtime.h>
#include <math.h>

#define NPIX   4096
#define FDIM   64
#define BATCH  2
#define SPLIT  16
#define CHUNK  (NPIX / SPLIT)      // 256
#define NTILE  (CHUNK / 16)        // 16 m-tiles of 16
#define BLKN   256                 // n-rows per block (8 waves x 32)
#define PITCH  72                  // shorts per LDS X row (64 + 8 pad)

typedef __attribute__((ext_vector_type(8))) short short8;
typedef __attribute__((ext_vector_type(4))) float floatx4;

__device__ __forceinline__ float exp2f_(float x) { return __builtin_amdgcn_exp2f(x); }

// round-to-nearest-even fp32 -> bf16
__device__ __forceinline__ short f2bf(float x) {
    union { float f; unsigned u; } c; c.f = x;
    unsigned r = (c.u + 0x7FFFu + ((c.u >> 16) & 1u)) >> 16;
    return (short)r;
}

// ---------------- LAB helpers ----------------
__device__ __forceinline__ float gamma_expand(float u) {
    return u > 0.04045f ? powf((u + 0.055f) * (1.0f / 1.055f), 2.4f)
                        : u * (1.0f / 12.92f);
}
__device__ __forceinline__ float lab_f(float t) {
    return t > 0.008856f ? cbrtf(t) : 7.787f * t + (16.0f / 116.0f);
}

// ---------------- Kernel 1: prep = feat transpose->bf16 (blocks 0..255) + LAB (blocks 256..319) ----
// f0t/f1t: [b][n][f] bf16; f0t pre-scaled by log2(e)/0.07 (logits in log2 space).
__global__ __launch_bounds__(256) void prep_kernel(
    const float* __restrict__ rgb0, const float* __restrict__ rgb1,
    const float* __restrict__ feat0, const float* __restrict__ feat1,
    float* __restrict__ lab0, float* __restrict__ lab1,
    short* __restrict__ f0t, short* __restrict__ f1t,
    float* __restrict__ out)
{
    int bid = blockIdx.x;
    int tid = threadIdx.x;

    if (bid < 256) {
        __shared__ short Tsm[64 * 72];
        int pair = bid >> 6;            // 0..3
        int tensor = pair >> 1;         // 0: f0, 1: f1
        int bb = pair & 1;
        int n0 = (bid & 63) * 64;
        const float* src = (tensor ? feat1 : feat0) + (size_t)bb * FDIM * NPIX;
        short* dst = (tensor ? f1t : f0t) + (size_t)bb * NPIX * FDIM;
        float scale = tensor ? 1.0f : (1.442695040888963f / 0.07f);

        int f = tid >> 2;
        int slot = tid & 3;
        #pragma unroll
        for (int i = 0; i < 4; ++i) {
            int col4 = slot * 4 + i;
            int noff = col4 * 4;
            float4 v = *(const float4*)&src[(size_t)f * NPIX + n0 + noff];
            Tsm[(noff + 0) * 72 + f] = f2bf(v.x * scale);
            Tsm[(noff + 1) * 72 + f] = f2bf(v.y * scale);
            Tsm[(noff + 2) * 72 + f] = f2bf(v.z * scale);
            Tsm[(noff + 3) * 72 + f] = f2bf(v.w * scale);
        }
        __syncthreads();
        #pragma unroll
        for (int i = 0; i < 2; ++i) {
            int idx = i * 256 + tid;
            int row = idx >> 3, ch = idx & 7;
            *(short8*)&dst[(size_t)(n0 + row) * FDIM + ch * 8] =
                *(const short8*)&Tsm[row * 72 + ch * 8];
        }
        return;
    }

    if (bid == 256 && tid == 0) out[0] = 0.0f;   // zero-init for loss atomicAdd

    // LAB branch
    int gid = (bid - 256) * 256 + tid;     // 0 .. 16383
    int img = gid / (BATCH * NPIX);
    int rem = gid - img * (BATCH * NPIX);
    int b = rem / NPIX;
    int n = rem - b * NPIX;
    const float* rgb = img ? rgb1 : rgb0;
    float* lab = img ? lab1 : lab0;

    size_t i0 = (size_t)(b * 3 + 0) * NPIX + n;
    size_t i1 = (size_t)(b * 3 + 1) * NPIX + n;
    size_t i2 = (size_t)(b * 3 + 2) * NPIX + n;

    float r = gamma_expand(rgb[i0] + 0.5f);
    float g = gamma_expand(rgb[i1] + 0.5f);
    float bl = gamma_expand(rgb[i2] + 0.5f);

    float X = (0.412453f * r + 0.357580f * g + 0.180423f * bl) * (1.0f / 0.95047f);
    float Y = (0.212671f * r + 0.715160f * g + 0.072169f * bl);
    float Z = (0.019334f * r + 0.119193f * g + 0.950227f * bl) * (1.0f / 1.08883f);

    float fx = lab_f(X), fy = lab_f(Y), fz = lab_f(Z);
    float L = 116.0f * fy - 16.0f;
    float a = 500.0f * (fx - fy);
    float bb2 = 200.0f * (fy - fz);

    lab[i0] = (L - 50.0f) * (1.0f / 100.0f);
    lab[i1] = a * (1.0f / 110.0f);
    lab[i2] = bb2 * (1.0f / 110.0f);
}

// ---------------- Kernel 2: MFMA attn — X chunk staged ONCE per block in LDS, 8 waves share ----------------
// mfma(X=f1 rows m, Y=f0 rows n): D[row=q*4+r <-> m][col=lane&15 <-> n]  (bench-verified R5-R8).
// 512-thread blocks (8 waves), grid 512 -> 2 blocks/CU, 4 waves/SIMD. One barrier total; main
// loop is ds_read_b128 + MFMA + softmax only (zero global loads). Pad-72 rows -> uniform banks.
__global__ __launch_bounds__(512, 4) void attn_kernel(
    const short* __restrict__ f0t, const short* __restrict__ f1t,
    const float* __restrict__ lab1ws, float* __restrict__ partials)
{
    __shared__ short Xs[CHUNK * PITCH];    // 36 KB
    __shared__ float Lt[3 * CHUNK];        // 3 KB

    int bid = blockIdx.x;
    int rowblk = bid & 15;                 // 16 rowblocks of 256 n
    int chunk = (bid >> 4) & (SPLIT - 1);
    int b = bid >> 8;
    int tid = threadIdx.x;
    int wv = tid >> 6;                     // 0..7
    int l = tid & 63;
    int c = l & 15;
    int q = l >> 4;

    int n_base = rowblk * BLKN + wv * 32;  // this wave: rows n_base+c (g0), n_base+16+c (g1)
    int m_base = chunk * CHUNK;

    // stage labels for the m-chunk (3 x 256 floats)
    if (tid < 192) {
        int cc = tid >> 6;
        int m4 = tid & 63;
        *(float4*)&Lt[cc * CHUNK + m4 * 4] =
            *(const float4*)&lab1ws[(size_t)(b * 3 + cc) * NPIX + m_base + m4 * 4];
    }

    // stage X: 256 rows x 64 bf16 = 2048 chunks of 16B; straight copy, padded rows
    {
        const short8* src = (const short8*)(f1t + ((size_t)b * NPIX + m_base) * FDIM);
        #pragma unroll
        for (int i = 0; i < 4; ++i) {
            int g = i * 512 + tid;         // 0..2047
            int m = g >> 3, kc = g & 7;
            *(short8*)&Xs[m * PITCH + kc * 8] = src[g];
        }
    }

    // Y fragments (f0, n-rows), 2 groups, straight from global (one-time)
    short8 ya[2], yb[2];
    #pragma unroll
    for (int g = 0; g < 2; ++g) {
        const short8* yp = (const short8*)(f0t +
            ((size_t)b * NPIX + n_base + g * 16 + c) * FDIM + q * 8);
        ya[g] = yp[0];
        yb[g] = yp[4];
    }

    __syncthreads();

    float ms[2], sum[2], aA[2], aB[2], aC[2];
    #pragma unroll
    for (int g = 0; g < 2; ++g) {
        ms[g] = -INFINITY; sum[g] = 0.0f;
        aA[g] = 0.0f; aB[g] = 0.0f; aC[g] = 0.0f;
    }

    #pragma unroll
    for (int t = 0; t < NTILE; ++t) {
        const short* xr = &Xs[(t * 16 + c) * PITCH + q * 8];
        short8 xa = *(const short8*)xr;
        short8 xb = *(const short8*)(xr + 32);

        floatx4 z = (floatx4)(0.0f);
        floatx4 acc[2];
        #pragma unroll
        for (int g = 0; g < 2; ++g) {
            acc[g] = __builtin_amdgcn_mfma_f32_16x16x32_bf16(xa, ya[g], z, 0, 0, 0);
            acc[g] = __builtin_amdgcn_mfma_f32_16x16x32_bf16(xb, yb[g], acc[g], 0, 0, 0);
        }

        // labels for this tile: m = t*16 + q*4 + j (broadcast within quad)
        float4 lA = *(const float4*)&Lt[0 * CHUNK + t * 16 + q * 4];
        float4 lB = *(const float4*)&Lt[1 * CHUNK + t * 16 + q * 4];
        float4 lC = *(const float4*)&Lt[2 * CHUNK + t * 16 + q * 4];

        #pragma unroll
        for (int g = 0; g < 2; ++g) {
            float L0 = acc[g][0], L1 = acc[g][1], L2 = acc[g][2], L3 = acc[g][3];
            float tmax = fmaxf(fmaxf(L0, L1), fmaxf(L2, L3));
            float nm = fmaxf(ms[g], tmax);
            float sc = exp2f_(ms[g] - nm);
            float p0 = exp2f_(L0 - nm);
            float p1 = exp2f_(L1 - nm);
            float p2 = exp2f_(L2 - nm);
            float p3 = exp2f_(L3 - nm);
            sum[g] = sum[g] * sc + ((p0 + p1) + (p2 + p3));
            aA[g] = aA[g] * sc + ((p0 * lA.x + p1 * lA.y) + (p2 * lA.z + p3 * lA.w));
            aB[g] = aB[g] * sc + ((p0 * lB.x + p1 * lB.y) + (p2 * lB.z + p3 * lB.w));
            aC[g] = aC[g] * sc + ((p0 * lC.x + p1 * lC.y) + (p2 * lC.z + p3 * lC.w));
            ms[g] = nm;
        }
    }

    // butterfly merge across q (lane bits 4-5): 2 steps, 2 groups
    #pragma unroll
    for (int mask = 16; mask <= 32; mask <<= 1) {
        #pragma unroll
        for (int g = 0; g < 2; ++g) {
            float om = __shfl_xor(ms[g], mask, 64);
            float os = __shfl_xor(sum[g], mask, 64);
            float oA = __shfl_xor(aA[g], mask, 64);
            float oB = __shfl_xor(aB[g], mask, 64);
            float oC = __shfl_xor(aC[g], mask, 64);
            float nm = fmaxf(ms[g], om);
            float w1 = exp2f_(ms[g] - nm);
            float w2 = exp2f_(om - nm);
            sum[g] = sum[g] * w1 + os * w2;
            aA[g] = aA[g] * w1 + oA * w2;
            aB[g] = aB[g] * w1 + oB * w2;
            aC[g] = aC[g] * w1 + oC * w2;
            ms[g] = nm;
        }
    }

    if (q == 0) {
        size_t pbase = (size_t)(b * SPLIT + chunk) * 5 * NPIX;
        #pragma unroll
        for (int g = 0; g < 2; ++g) {
            int n = n_base + g * 16 + c;
            partials[pbase + 0 * NPIX + n] = ms[g];
            partials[pbase + 1 * NPIX + n] = sum[g];
            partials[pbase + 2 * NPIX + n] = aA[g];
            partials[pbase + 3 * NPIX + n] = aB[g];
            partials[pbase + 4 * NPIX + n] = aC[g];
        }
    }
}

// ---------------- Kernel 3: merge chunks, diff, L1+Huber, reduce ----------------
__global__ void loss_kernel(const float* __restrict__ partials,
                            const float* __restrict__ lab0ws,
                            float* __restrict__ out)
{
    int gid = blockIdx.x * blockDim.x + threadIdx.x;   // 0..8191
    int b = gid >> 12;
    int n = gid & (NPIX - 1);

    float M = -INFINITY;
    #pragma unroll
    for (int ch = 0; ch < SPLIT; ++ch)
        M = fmaxf(M, partials[((size_t)(b * SPLIT + ch) * 5 + 0) * NPIX + n]);
    float S = 0.0f, A0 = 0.0f, A1 = 0.0f, A2 = 0.0f;
    #pragma unroll
    for (int ch = 0; ch < SPLIT; ++ch) {
        size_t base = (size_t)(b * SPLIT + ch) * 5 * NPIX + n;
        float w = exp2f_(partials[base + 0 * NPIX] - M);
        S  += partials[base + 1 * NPIX] * w;
        A0 += partials[base + 2 * NPIX] * w;
        A1 += partials[base + 3 * NPIX] * w;
        A2 += partials[base + 4 * NPIX] * w;
    }
    float inv_s = 1.0f / S;
    float d0 = A0 * inv_s - lab0ws[(size_t)(b * 3 + 0) * NPIX + n];
    float d1 = A1 * inv_s - lab0ws[(size_t)(b * 3 + 1) * NPIX + n];
    float d2 = A2 * inv_s - lab0ws[(size_t)(b * 3 + 2) * NPIX + n];

    float val = 0.0f;
    #pragma unroll
    for (int cc = 0; cc < 3; ++cc) {
        float d = (cc == 0) ? d0 : (cc == 1) ? d1 : d2;
        float ad = fabsf(d);
        float hub = (ad < 1.0f) ? 0.5f * ad * ad : ad - 0.5f;
        val += ad + hub;
    }

    #pragma unroll
    for (int off = 32; off > 0; off >>= 1)
        val += __shfl_down(val, off);

    __shared__ float wsum[4];
    int lane = threadIdx.x & 63;
    int wave = threadIdx.x >> 6;
    if (lane == 0) wsum[wave] = val;
    __syncthreads();
    if (threadIdx.x == 0) {
        float s = wsum[0] + wsum[1] + wsum[2] + wsum[3];
        atomicAdd(out, s * (1.0f / 8192.0f));
    }
}

// ---------------- launcher ----------------
extern "C" void kernel_launch(void* const* d_in, const int* in_sizes, int n_in,
                              void* d_out, int out_size, void* d_ws, size_t ws_size,
                              hipStream_t stream) {
    const float* rgb0  = (const float*)d_in[0];
    const float* rgb1  = (const float*)d_in[1];
    const float* feat0 = (const float*)d_in[2];
    const float* feat1 = (const float*)d_in[3];
    float* out = (float*)d_out;
    float* ws  = (float*)d_ws;

    float* lab0 = ws;                         // 24576 floats
    float* lab1 = ws + 24576;                 // 24576 floats
    float* partials = ws + 49152;             // 2*16*5*4096 = 655360 floats
    short* f0t = (short*)(ws + 49152 + 655360);
    short* f1t = f0t + (size_t)BATCH * NPIX * FDIM;

    prep_kernel<<<320, 256, 0, stream>>>(rgb0, rgb1, feat0, feat1, lab0, lab1, f0t, f1t, out);

    int attn_grid = BATCH * SPLIT * (NPIX / BLKN);   // 512 blocks x 512 threads
    attn_kernel<<<attn_grid, 512, 0, stream>>>(f0t, f1t, lab1, partials);

    loss_kernel<<<(BATCH * NPIX) / 256, 256, 0, stream>>>(partials, lab0, out);
}